// Round 2
// baseline (106107.031 us; speedup 1.0000x reference)
//
#include <hip/hip_runtime.h>
#include <math.h>

// ---------------------------------------------------------------------------
// 9-layer LSTM, wavefront-pipelined persistent kernel.
//   T=2048, B=32, IN=128, H=256, OUT=2, L=9
// Grid: 9 layers x 16 WGs + 1 output WG = 145 blocks, 256 thr.
// 149.5 KB LDS/WG forces 1 WG/CU -> all 145 blocks co-resident on 256 CUs
// (spread is structurally guaranteed), so cross-WG spin-flags are safe;
// sticky spin bail-out caps any failure at ~0.1 s instead of a hang.
// Layer-l WG g owns hidden units [g*16, g*16+16) (all 4 gates = 64 rows of 4H).
// Weight slice [64][K<=512] fp32 resident in LDS for the whole run.
// Cross-WG dataflow: hbuf ring (depth 4) + ready[layer][t] counters
// (agent-scope acquire/release). c-state lives in registers.
// ---------------------------------------------------------------------------

#define T_LEN   2048
#define B_SZ    32
#define IN_D    128
#define H_D     256
#define OUT_D   2
#define NL      9
#define WPL     16          // workgroups per layer
#define UPW     16          // hidden units per WG
#define RING    4           // h ring depth (steps); correctness needs >=2
#define NTHR    256
#define CK      64          // K-chunk staged per phase
#define WS      516         // W LDS row stride (floats): broadcast-friendly
#define HS      68          // h LDS row stride (floats): 2-way max (free)
#define NPWG    (NL*WPL)    // 144 producer WGs; block 144 = output stage
#define SPIN_CAP 2000000    // sticky bail-out: never hang the harness

// d_ws layout:
//   [0, 81920)             int   ready[NL+1][T_LEN]   (memset 0 each launch)
//   [81920, 81920+1.18MB)  float hbuf[NL][RING][B_SZ][H_D]

__device__ __forceinline__ bool spin_until(int* p, int target) {
  for (int i = 0; i < SPIN_CAP; ++i) {
    if (__hip_atomic_load(p, __ATOMIC_ACQUIRE, __HIP_MEMORY_SCOPE_AGENT) >= target)
      return true;
    __builtin_amdgcn_s_sleep(2);
  }
  return false;  // give up (result fails validation but harness never hangs)
}

__device__ __forceinline__ float sigf(float x) { return 1.0f / (1.0f + __expf(-x)); }

extern "C" __global__ void __launch_bounds__(NTHR, 1)
lstm_pipe(const float* __restrict__ x,    const float* __restrict__ Wih0,
          const float* __restrict__ WihR, const float* __restrict__ Whh,
          const float* __restrict__ bvec, const float* __restrict__ Wo,
          const float* __restrict__ bo,   float* __restrict__ out,
          int* __restrict__ ready,        float* __restrict__ hbuf)
{
  // 132096 B weights + 17408 B h double-buffer = 149504 B LDS (<=160 KiB/CU)
  __shared__ float Wl[64 * WS];
  __shared__ float hl[2 * B_SZ * HS];

  const int tid = threadIdx.x;
  const int wg  = blockIdx.x;

  if (wg < NPWG) {
    // ------------------------- producer workgroup -------------------------
    const int l   = wg / WPL;
    const int g   = wg % WPL;
    const int u   = tid >> 4;        // 0..15 : local hidden unit
    const int bt  = tid & 15;        // batches bt and bt+16
    const int Kin = (l == 0) ? IN_D : H_D;   // below-input width
    const int K   = Kin + H_D;               // 384 or 512
    const int nch = K / CK;                  // 6 or 8 chunks

    // ---- load weight slice into LDS: lds row lr=gt*16+uu <- global row
    //      r = gt*H + g*16 + uu ; k<Kin from Wih, k>=Kin from Whh[l]
    for (int lr = 0; lr < 64; ++lr) {
      const int gt = lr >> 4, uu = lr & 15;
      const int r  = gt * H_D + g * UPW + uu;
      float* wrow = Wl + lr * WS;
      const float* srcI = (l == 0) ? (Wih0 + (size_t)r * IN_D)
                                   : (WihR + ((size_t)(l - 1) * 4 * H_D + r) * H_D);
      for (int k = tid; k < Kin; k += NTHR) wrow[k] = srcI[k];
      const float* srcH = Whh + ((size_t)l * 4 * H_D + r) * H_D;
      for (int k = tid; k < H_D; k += NTHR) wrow[Kin + k] = srcH[k];
    }
    float bias[4];
#pragma unroll
    for (int gt = 0; gt < 4; ++gt)
      bias[gt] = bvec[(size_t)l * 4 * H_D + gt * H_D + g * UPW + u];

    float c0 = 0.f, c1 = 0.f;
    bool alive = true;               // meaningful on tid 0 only
    __syncthreads();

    for (int t = 0; t < T_LEN; ++t) {
      // ---- wait: own h(t-1) written, input h(t) ready, ring slot free ----
      if (tid == 0 && alive) {
        if (t > 0)            alive = spin_until(&ready[l * T_LEN + (t - 1)], WPL) && alive;
        if (l > 0 && alive)   alive = spin_until(&ready[(l - 1) * T_LEN + t], WPL) && alive;
        if (t >= RING && alive) {
          const int need = (l == NL - 1) ? 1 : WPL;  // consumer of hbuf[l]
          alive = spin_until(&ready[(l + 1) * T_LEN + (t - RING)], need) && alive;
        }
      }
      __syncthreads();
      __threadfence();   // acquire: make producers' hbuf stores visible

      // ---- chunk source resolver ----
      auto fetch = [&](int ch, float4& a0, float4& a1) {
        const int kbase = ch * CK;
        const float* src = nullptr;
        int stride = 0;
        bool skip = false;
        if (kbase < Kin) {           // "below" input: x or hbuf[l-1][t]
          if (l == 0) { src = x + (size_t)t * B_SZ * IN_D + kbase; stride = IN_D; }
          else { src = hbuf + (((size_t)(l - 1) * RING + (t % RING)) * B_SZ * H_D) + kbase; stride = H_D; }
        } else {                     // own h(t-1)
          if (t == 0) skip = true;   // h(-1)=0: stage zeros, keep flow uniform
          else { src = hbuf + (((size_t)l * RING + ((t - 1) % RING)) * B_SZ * H_D) + (kbase - Kin); stride = H_D; }
        }
        if (skip) { a0 = make_float4(0.f, 0.f, 0.f, 0.f); a1 = a0; }
        else {
          const int i0 = tid,        b0i = i0 >> 4, k0 = (i0 & 15) * 4;
          const int i1 = NTHR + tid, b1i = i1 >> 4, k1 = (i1 & 15) * 4;
          a0 = *(const float4*)(src + (size_t)b0i * stride + k0);
          a1 = *(const float4*)(src + (size_t)b1i * stride + k1);
        }
      };

      float acc[2][4] = {{0.f, 0.f, 0.f, 0.f}, {0.f, 0.f, 0.f, 0.f}};
      float4 pf0, pf1;

      // prologue: stage chunk 0 into buffer 0
      fetch(0, pf0, pf1);
      {
        const int i0 = tid,        i1 = NTHR + tid;
        *(float4*)(hl + (i0 >> 4) * HS + (i0 & 15) * 4) = pf0;
        *(float4*)(hl + (i1 >> 4) * HS + (i1 & 15) * 4) = pf1;
      }
      __syncthreads();

      int cur = 0;
      for (int ch = 0; ch < nch; ++ch) {
        if (ch + 1 < nch) fetch(ch + 1, pf0, pf1);   // overlap HBM/L2 latency
        const float* hrow0 = hl + cur * (B_SZ * HS) + bt * HS;
        const float* hrow1 = hrow0 + 16 * HS;
        const int kbase = ch * CK;
#pragma unroll 4
        for (int kk = 0; kk < CK; kk += 4) {
          const float4 h0 = *(const float4*)(hrow0 + kk);
          const float4 h1 = *(const float4*)(hrow1 + kk);
#pragma unroll
          for (int gt = 0; gt < 4; ++gt) {
            const float4 wv = *(const float4*)(Wl + (gt * UPW + u) * WS + kbase + kk);
            acc[0][gt] += h0.x * wv.x + h0.y * wv.y + h0.z * wv.z + h0.w * wv.w;
            acc[1][gt] += h1.x * wv.x + h1.y * wv.y + h1.z * wv.z + h1.w * wv.w;
          }
        }
        __syncthreads();                 // done reading buf[cur]
        if (ch + 1 < nch) {
          float* nb = hl + (cur ^ 1) * (B_SZ * HS);
          const int i0 = tid, i1 = NTHR + tid;
          *(float4*)(nb + (i0 >> 4) * HS + (i0 & 15) * 4) = pf0;
          *(float4*)(nb + (i1 >> 4) * HS + (i1 & 15) * 4) = pf1;
          cur ^= 1;
          __syncthreads();               // buf[cur] ready for next compute
        }
      }

      // ---- gates: i,f,g,o (PyTorch order) ----
      float hv0, hv1;
      {
        const float gi = sigf(acc[0][0] + bias[0]);
        const float gf = sigf(acc[0][1] + bias[1]);
        const float gg = tanhf(acc[0][2] + bias[2]);
        const float go = sigf(acc[0][3] + bias[3]);
        c0 = gf * c0 + gi * gg;
        hv0 = go * tanhf(c0);
      }
      {
        const float gi = sigf(acc[1][0] + bias[0]);
        const float gf = sigf(acc[1][1] + bias[1]);
        const float gg = tanhf(acc[1][2] + bias[2]);
        const float go = sigf(acc[1][3] + bias[3]);
        c1 = gf * c1 + gi * gg;
        hv1 = go * tanhf(c1);
      }

      float* dst = hbuf + ((size_t)l * RING + (t % RING)) * B_SZ * H_D + g * UPW + u;
      dst[(size_t)bt * H_D]        = hv0;
      dst[(size_t)(bt + 16) * H_D] = hv1;

      __threadfence();  // release: flush h stores to device scope
      __syncthreads();
      if (tid == 0)
        __hip_atomic_fetch_add(&ready[l * T_LEN + t], 1,
                               __ATOMIC_RELEASE, __HIP_MEMORY_SCOPE_AGENT);
    }
  } else {
    // ------------------------- output-projection WG -----------------------
    float* WoL = Wl;                 // [2][256]
    float* h8  = Wl + OUT_D * H_D;   // [32][257] (odd stride: conflict-free)
    for (int i = tid; i < OUT_D * H_D; i += NTHR) WoL[i] = Wo[i];
    const float bo0 = bo[0], bo1 = bo[1];
    bool alive = true;
    __syncthreads();

    for (int t = 0; t < T_LEN; ++t) {
      if (tid == 0 && alive)
        alive = spin_until(&ready[(NL - 1) * T_LEN + t], WPL) && alive;
      __syncthreads();
      __threadfence();

      const float* src = hbuf + ((size_t)(NL - 1) * RING + (t % RING)) * B_SZ * H_D;
      for (int i = tid; i < B_SZ * H_D; i += NTHR)
        h8[(i >> 8) * 257 + (i & 255)] = src[i];
      __syncthreads();

      if (tid < B_SZ * OUT_D) {
        const int bb = tid >> 1, o = tid & 1;
        float s = 0.f;
#pragma unroll 8
        for (int k = 0; k < H_D; ++k) s += h8[bb * 257 + k] * WoL[o * H_D + k];
        s += (o ? bo1 : bo0);
        out[(size_t)t * B_SZ * OUT_D + bb * OUT_D + o] = sigf(s);
      }
      __threadfence();
      __syncthreads();
      if (tid == 0)
        __hip_atomic_fetch_add(&ready[NL * T_LEN + t], 1,
                               __ATOMIC_RELEASE, __HIP_MEMORY_SCOPE_AGENT);
    }
  }
}

extern "C" void kernel_launch(void* const* d_in, const int* in_sizes, int n_in,
                              void* d_out, int out_size, void* d_ws, size_t ws_size,
                              hipStream_t stream) {
  const float* x    = (const float*)d_in[0];
  const float* Wih0 = (const float*)d_in[1];
  const float* WihR = (const float*)d_in[2];
  const float* Whh  = (const float*)d_in[3];
  const float* bv   = (const float*)d_in[4];
  const float* Wo   = (const float*)d_in[5];
  const float* bo   = (const float*)d_in[6];
  float* out = (float*)d_out;

  int*   ready = (int*)d_ws;
  float* hbuf  = (float*)((char*)d_ws + (size_t)(NL + 1) * T_LEN * sizeof(int));

  // flags must start at 0 every call (ws is poisoned 0xAA before each launch)
  hipMemsetAsync(d_ws, 0, (size_t)(NL + 1) * T_LEN * sizeof(int), stream);

  hipLaunchKernelGGL(lstm_pipe, dim3(NPWG + 1), dim3(NTHR), 0, stream,
                     x, Wih0, WihR, Whh, bv, Wo, bo, out, ready, hbuf);
}

// Round 3
// 46294.492 us; speedup vs baseline: 2.2920x; 2.2920x over previous
//
#include <hip/hip_runtime.h>
#include <math.h>

// ---------------------------------------------------------------------------
// 9-layer LSTM, wavefront-pipelined persistent kernel. Round 3.
//   T=2048, B=32, IN=128, H=256, OUT=2, L=9
// R2 finding: 106 ms, VALUBusy 11% -> sync-storm-bound. Every ACQUIRE poll
// emitted buffer_inv (L2 invalidate) and every RELEASE emitted buffer_wbl2
// (L2 writeback): ~40M polls -> FETCH 2.5GB, ~900K wbl2 -> WRITE 3.6GB.
// R3 fix: all cross-WG data goes through L3 (the XCD coherence point) with
// RELAXED agent atomics (no L2 cache-ops); exactly ONE acquire fence
// (buffer_inv) per WG per step, tid0 only; release = vmcnt(0) + relaxed add.
// ---------------------------------------------------------------------------

#define T_LEN   2048
#define B_SZ    32
#define IN_D    128
#define H_D     256
#define OUT_D   2
#define NL      9
#define WPL     16          // workgroups per layer
#define UPW     16          // hidden units per WG
#define RING    4           // h ring depth (steps); correctness needs >=2
#define NTHR    256
#define CK      64          // K-chunk staged per phase
#define WS      516         // W LDS row stride (floats)
#define HS      68          // h LDS row stride (floats)
#define NPWG    (NL*WPL)    // 144 producer WGs; block 144 = output stage
#define SPIN_CAP 2000000    // sticky bail-out: never hang the harness

// d_ws layout:
//   [0, 81920)             int   ready[NL+1][T_LEN]   (memset 0 each launch)
//   [81920, 81920+1.18MB)  float hbuf[NL][RING][B_SZ][H_D]

__device__ __forceinline__ int poll_flag(int* p) {
  // RMW executes at the device coherence point (L3): always fresh, and —
  // unlike an ACQUIRE load — emits no per-poll L2 invalidate.
  return __hip_atomic_fetch_add(p, 0, __ATOMIC_RELAXED, __HIP_MEMORY_SCOPE_AGENT);
}

__device__ __forceinline__ void sig_add(int* p) {
  __hip_atomic_fetch_add(p, 1, __ATOMIC_RELAXED, __HIP_MEMORY_SCOPE_AGENT);
}

__device__ __forceinline__ void st_l3(float* p, float v) {
  // store performed at L3: no dirty L2 line, visible to all XCDs
  __hip_atomic_store(p, v, __ATOMIC_RELAXED, __HIP_MEMORY_SCOPE_AGENT);
}

__device__ __forceinline__ float sigf(float x) { return 1.0f / (1.0f + __expf(-x)); }

extern "C" __global__ void __launch_bounds__(NTHR, 1)
lstm_pipe(const float* __restrict__ x,    const float* __restrict__ Wih0,
          const float* __restrict__ WihR, const float* __restrict__ Whh,
          const float* __restrict__ bvec, const float* __restrict__ Wo,
          const float* __restrict__ bo,   float* __restrict__ out,
          int* __restrict__ ready,        float* __restrict__ hbuf)
{
  // 132096 B weights + 17408 B h double-buffer = 149504 B LDS (<=160 KiB/CU)
  __shared__ float Wl[64 * WS];
  __shared__ float hl[2 * B_SZ * HS];
  __shared__ int   s_dead;            // sticky spin-timeout flag (wave0 only)

  const int tid = threadIdx.x;
  const int wg  = blockIdx.x;
  if (tid == 0) s_dead = 0;

  if (wg < NPWG) {
    // ------------------------- producer workgroup -------------------------
    const int l   = wg / WPL;
    const int g   = wg % WPL;
    const int u   = tid >> 4;        // 0..15 : local hidden unit
    const int bt  = tid & 15;        // batches bt and bt+16
    const int Kin = (l == 0) ? IN_D : H_D;   // below-input width
    const int K   = Kin + H_D;               // 384 or 512
    const int nch = K / CK;                  // 6 or 8 chunks

    // ---- load weight slice into LDS: lds row lr=gt*16+uu <- global row
    for (int lr = 0; lr < 64; ++lr) {
      const int gt = lr >> 4, uu = lr & 15;
      const int r  = gt * H_D + g * UPW + uu;
      float* wrow = Wl + lr * WS;
      const float* srcI = (l == 0) ? (Wih0 + (size_t)r * IN_D)
                                   : (WihR + ((size_t)(l - 1) * 4 * H_D + r) * H_D);
      for (int k = tid; k < Kin; k += NTHR) wrow[k] = srcI[k];
      const float* srcH = Whh + ((size_t)l * 4 * H_D + r) * H_D;
      for (int k = tid; k < H_D; k += NTHR) wrow[Kin + k] = srcH[k];
    }
    float bias[4];
#pragma unroll
    for (int gt = 0; gt < 4; ++gt)
      bias[gt] = bvec[(size_t)l * 4 * H_D + gt * H_D + g * UPW + u];

    float c0 = 0.f, c1 = 0.f;
    __syncthreads();

    for (int t = 0; t < T_LEN; ++t) {
      // ---- lane-parallel waits (wave 0): own h(t-1) / below h(t) / slot --
      if (tid < 64) {
        int* p  = nullptr; int tgt = 0;
        if (tid == 0 && t > 0)     { p = &ready[l * T_LEN + (t - 1)];        tgt = WPL; }
        if (tid == 1 && l > 0)     { p = &ready[(l - 1) * T_LEN + t];        tgt = WPL; }
        if (tid == 2 && t >= RING) { p = &ready[(l + 1) * T_LEN + (t - RING)];
                                     tgt = (l == NL - 1) ? 1 : WPL; }
        bool done = (p == nullptr) || (s_dead != 0);
        int  it = 0;
        while (!__all(done)) {
          if (!done) {
            if (poll_flag(p) >= tgt) done = true;
            else if (++it >= SPIN_CAP) { s_dead = 1; done = true; }
            else __builtin_amdgcn_s_sleep(1);
          }
        }
        // ONE acquire fence per WG per step: invalidate L1/L2 so hbuf reads
        // miss to L3 (which producers' agent-atomic stores made fresh).
        if (tid == 0) __builtin_amdgcn_fence(__ATOMIC_ACQUIRE, "agent");
      }
      __syncthreads();

      // ---- chunk source resolver ----
      auto fetch = [&](int ch, float4& a0, float4& a1) {
        const int kbase = ch * CK;
        const float* src = nullptr;
        int stride = 0;
        bool skip = false;
        if (kbase < Kin) {           // "below" input: x or hbuf[l-1][t]
          if (l == 0) { src = x + (size_t)t * B_SZ * IN_D + kbase; stride = IN_D; }
          else { src = hbuf + (((size_t)(l - 1) * RING + (t % RING)) * B_SZ * H_D) + kbase; stride = H_D; }
        } else {                     // own h(t-1)
          if (t == 0) skip = true;   // h(-1)=0
          else { src = hbuf + (((size_t)l * RING + ((t - 1) % RING)) * B_SZ * H_D) + (kbase - Kin); stride = H_D; }
        }
        if (skip) { a0 = make_float4(0.f, 0.f, 0.f, 0.f); a1 = a0; }
        else {
          const int i0 = tid,        b0i = i0 >> 4, k0 = (i0 & 15) * 4;
          const int i1 = NTHR + tid, b1i = i1 >> 4, k1 = (i1 & 15) * 4;
          a0 = *(const float4*)(src + (size_t)b0i * stride + k0);
          a1 = *(const float4*)(src + (size_t)b1i * stride + k1);
        }
      };

      float acc[2][4] = {{0.f, 0.f, 0.f, 0.f}, {0.f, 0.f, 0.f, 0.f}};
      float4 pf0, pf1;

      fetch(0, pf0, pf1);
      {
        const int i0 = tid,        i1 = NTHR + tid;
        *(float4*)(hl + (i0 >> 4) * HS + (i0 & 15) * 4) = pf0;
        *(float4*)(hl + (i1 >> 4) * HS + (i1 & 15) * 4) = pf1;
      }
      __syncthreads();

      int cur = 0;
      for (int ch = 0; ch < nch; ++ch) {
        if (ch + 1 < nch) fetch(ch + 1, pf0, pf1);   // overlap L3 latency
        const float* hrow0 = hl + cur * (B_SZ * HS) + bt * HS;
        const float* hrow1 = hrow0 + 16 * HS;
        const int kbase = ch * CK;
#pragma unroll 4
        for (int kk = 0; kk < CK; kk += 4) {
          const float4 h0 = *(const float4*)(hrow0 + kk);
          const float4 h1 = *(const float4*)(hrow1 + kk);
#pragma unroll
          for (int gt = 0; gt < 4; ++gt) {
            const float4 wv = *(const float4*)(Wl + (gt * UPW + u) * WS + kbase + kk);
            acc[0][gt] += h0.x * wv.x + h0.y * wv.y + h0.z * wv.z + h0.w * wv.w;
            acc[1][gt] += h1.x * wv.x + h1.y * wv.y + h1.z * wv.z + h1.w * wv.w;
          }
        }
        __syncthreads();
        if (ch + 1 < nch) {
          float* nb = hl + (cur ^ 1) * (B_SZ * HS);
          const int i0 = tid, i1 = NTHR + tid;
          *(float4*)(nb + (i0 >> 4) * HS + (i0 & 15) * 4) = pf0;
          *(float4*)(nb + (i1 >> 4) * HS + (i1 & 15) * 4) = pf1;
          cur ^= 1;
          __syncthreads();
        }
      }

      // ---- gates: i,f,g,o (PyTorch order) ----
      float hv0, hv1;
      {
        const float gi = sigf(acc[0][0] + bias[0]);
        const float gf = sigf(acc[0][1] + bias[1]);
        const float gg = tanhf(acc[0][2] + bias[2]);
        const float go = sigf(acc[0][3] + bias[3]);
        c0 = gf * c0 + gi * gg;
        hv0 = go * tanhf(c0);
      }
      {
        const float gi = sigf(acc[1][0] + bias[0]);
        const float gf = sigf(acc[1][1] + bias[1]);
        const float gg = tanhf(acc[1][2] + bias[2]);
        const float go = sigf(acc[1][3] + bias[3]);
        c1 = gf * c1 + gi * gg;
        hv1 = go * tanhf(c1);
      }

      float* dst = hbuf + ((size_t)l * RING + (t % RING)) * B_SZ * H_D + g * UPW + u;
      st_l3(&dst[(size_t)bt * H_D],        hv0);   // L3-direct: no dirty L2
      st_l3(&dst[(size_t)(bt + 16) * H_D], hv1);

      // release: wait own stores performed at L3, then relaxed flag add
      asm volatile("s_waitcnt vmcnt(0)" ::: "memory");
      __syncthreads();
      if (tid == 0) sig_add(&ready[l * T_LEN + t]);
    }
  } else {
    // ------------------------- output-projection WG -----------------------
    float* WoL = Wl;                 // [2][256]
    float* h8  = Wl + OUT_D * H_D;   // [32][257] (odd stride: conflict-free)
    for (int i = tid; i < OUT_D * H_D; i += NTHR) WoL[i] = Wo[i];
    const float bo0 = bo[0], bo1 = bo[1];
    __syncthreads();

    for (int t = 0; t < T_LEN; ++t) {
      if (tid < 64) {
        bool done = (tid != 0) || (s_dead != 0);
        int  it = 0;
        while (!__all(done)) {
          if (!done) {
            if (poll_flag(&ready[(NL - 1) * T_LEN + t]) >= WPL) done = true;
            else if (++it >= SPIN_CAP) { s_dead = 1; done = true; }
            else __builtin_amdgcn_s_sleep(1);
          }
        }
        if (tid == 0) __builtin_amdgcn_fence(__ATOMIC_ACQUIRE, "agent");
      }
      __syncthreads();

      const float* src = hbuf + ((size_t)(NL - 1) * RING + (t % RING)) * B_SZ * H_D;
      for (int i = tid; i < B_SZ * H_D; i += NTHR)
        h8[(i >> 8) * 257 + (i & 255)] = src[i];
      __syncthreads();

      if (tid < B_SZ * OUT_D) {
        const int bb = tid >> 1, o = tid & 1;
        float s = 0.f;
#pragma unroll 8
        for (int k = 0; k < H_D; ++k) s += h8[bb * 257 + k] * WoL[o * H_D + k];
        s += (o ? bo1 : bo0);
        st_l3(&out[(size_t)t * B_SZ * OUT_D + bb * OUT_D + o], sigf(s));
      }
      asm volatile("s_waitcnt vmcnt(0)" ::: "memory");
      __syncthreads();
      if (tid == 0) sig_add(&ready[NL * T_LEN + t]);
    }
  }
}

extern "C" void kernel_launch(void* const* d_in, const int* in_sizes, int n_in,
                              void* d_out, int out_size, void* d_ws, size_t ws_size,
                              hipStream_t stream) {
  const float* x    = (const float*)d_in[0];
  const float* Wih0 = (const float*)d_in[1];
  const float* WihR = (const float*)d_in[2];
  const float* Whh  = (const float*)d_in[3];
  const float* bv   = (const float*)d_in[4];
  const float* Wo   = (const float*)d_in[5];
  const float* bo   = (const float*)d_in[6];
  float* out = (float*)d_out;

  int*   ready = (int*)d_ws;
  float* hbuf  = (float*)((char*)d_ws + (size_t)(NL + 1) * T_LEN * sizeof(int));

  // flags must start at 0 every call (ws is poisoned 0xAA before each launch)
  hipMemsetAsync(d_ws, 0, (size_t)(NL + 1) * T_LEN * sizeof(int), stream);

  hipLaunchKernelGGL(lstm_pipe, dim3(NPWG + 1), dim3(NTHR), 0, stream,
                     x, Wih0, WihR, Whh, bv, Wo, bo, out, ready, hbuf);
}

// Round 8
// 8869.247 us; speedup vs baseline: 11.9635x; 5.2197x over previous
//
#include <hip/hip_runtime.h>
#include <hip/hip_bf16.h>
#include <math.h>

// ---------------------------------------------------------------------------
// 9-layer LSTM, wavefront-pipelined persistent kernel. Round 8 (= R7 resubmit).
//   T=2048, B=32, IN=128, H=256, OUT=2, L=9
// R6 finding: absmax=nan. Root cause: A-tile h-staging wrote ONE v8s (8
// ushorts) per 16-column slab -> holes [sc*16+8, sc*16+16) of uninitialized
// LDS (NaN bit patterns) fed the MFMA. Fix: stage TWO v8s per slab (and two
// zero-writes on the t==0 path). Nothing else changed from R4/R6:
//   8 WGs/layer (32 units each); weights VGPR-resident as MFMA B-fragments
//   (16 x bf16x8/lane); h_cat in LDS as bf16 A-tile [32][512] (K-padded for
//   layer 0); 8 waves x 32 mfma_f32_16x16x32_bf16; gate preacts via 16KB LDS
//   exchange; fp32 gate math; h packed bf16x2 stored L3-direct.
// Sync fabric (validated R3, absmax 0.0): relaxed L3 atomics, 1 acquire
// fence/WG/step, release = vmcnt(0) + relaxed flag add, sticky spin bail-out.
// Grid: 72 producers + 1 output WG = 73 blocks x 512 thr; LDS >80KiB ->
// 1 WG/CU (co-residency structurally guaranteed on 256 CUs).
// ---------------------------------------------------------------------------

#define T_LEN   2048
#define B_SZ    32
#define IN_D    128
#define H_D     256
#define OUT_D   2
#define NL      9
#define WPL     8           // workgroups per layer
#define UPW     32          // hidden units per WG
#define RING    4           // h ring depth (steps)
#define NTHR    512
#define NPWG    (NL*WPL)    // 72 producers; block 72 = output stage
#define SPIN_CAP 2000000    // sticky bail-out: never hang the harness

typedef short v8s __attribute__((ext_vector_type(8)));   // 8 x bf16 (4 VGPR)
typedef float v4f __attribute__((ext_vector_type(4)));   // MFMA accumulator

// d_ws layout:
//   [0, 81920)            int    ready[NL+1][T_LEN]   (memset 0 each launch)
//   [81920, +589824)      ushort hbuf[NL][RING][B_SZ][H_D]  (bf16 bits)

__device__ __forceinline__ float sigf(float x) { return 1.0f / (1.0f + __expf(-x)); }

__device__ __forceinline__ unsigned short f2bf(float f) {
  __hip_bfloat16 b = __float2bfloat16(f);
  return __builtin_bit_cast(unsigned short, b);
}
__device__ __forceinline__ float bf2f(unsigned short u) {
  unsigned int v = ((unsigned int)u) << 16;
  return __builtin_bit_cast(float, v);
}

extern "C" __global__ void __launch_bounds__(NTHR, 1)
lstm_pipe(const float* __restrict__ x,    const float* __restrict__ Wih0,
          const float* __restrict__ WihR, const float* __restrict__ Whh,
          const float* __restrict__ bvec, const float* __restrict__ Wo,
          const float* __restrict__ bo,   float* __restrict__ out,
          int* __restrict__ ready,        unsigned short* __restrict__ hbuf)
{
  // A-tile 37376B + gate-buffer 17408B + pad 28800B = 83588B  (>80KiB -> 1 WG/CU)
  __shared__ unsigned short Ash[32][584];   // [batch][K=512 +72 pad] bf16
  __shared__ float          Gb[4][32][34];  // [gate][batch][32 units +2 pad]
  __shared__ float          padL[7200];     // occupancy clamp (kept alive below)
  __shared__ int            s_dead;

  const int tid = threadIdx.x;
  const int wg  = blockIdx.x;
  if (tid == 0) s_dead = 0;
  if (wg == 0x7fffffff) padL[tid] = 0.f;    // opaque-false: keeps padL allocated

  if (wg < NPWG) {
    // ------------------------- producer workgroup -------------------------
    const int l  = wg / WPL, g = wg % WPL;
    const int w  = tid >> 6;          // wave 0..7 -> N-tile (= 16 gate rows)
    const int ln = tid & 63;
    const int cc = ln & 15;           // MFMA col / A-row lane index
    const int kq = ln >> 4;           // K-quarter

    // ---- W as permanent B-fragments: lane holds W[grow][ks*32+kq*8 .. +7]
    v8s wfrag[16];
    {
      const int nIdx = w * 16 + cc;            // 0..127 local gate-row
      const int gate = nIdx >> 5, uu = nIdx & 31;
      const int grow = gate * H_D + g * UPW + uu;
#pragma unroll
      for (int ks = 0; ks < 16; ++ks) {
        v8s p;
#pragma unroll
        for (int j = 0; j < 8; ++j) {
          const int k = ks * 32 + kq * 8 + j;  // concat-K index
          float wv = 0.f;
          if (l == 0) {                        // [x(128) | h(256) | zero(128)]
            if (k < IN_D)            wv = Wih0[(size_t)grow * IN_D + k];
            else if (k < IN_D + H_D) wv = Whh[(size_t)grow * H_D + (k - IN_D)];
          } else {                             // [h_below(256) | h_own(256)]
            if (k < H_D) wv = WihR[((size_t)(l - 1) * 4 * H_D + grow) * H_D + k];
            else         wv = Whh[((size_t)l * 4 * H_D + grow) * H_D + (k - H_D)];
          }
          p[j] = (short)f2bf(wv);
        }
        wfrag[ks] = p;
      }
    }

    // ---- epilogue mapping: thread -> units {2*a2, 2*a2+1}, batch mm ----
    const int a2 = tid & 15, mm = tid >> 4;    // mm 0..31
    float bs[4][2];
#pragma unroll
    for (int gt = 0; gt < 4; ++gt) {
      bs[gt][0] = bvec[(size_t)l * 4 * H_D + gt * H_D + g * UPW + 2 * a2];
      bs[gt][1] = bvec[(size_t)l * 4 * H_D + gt * H_D + g * UPW + 2 * a2 + 1];
    }
    float c0 = 0.f, c1 = 0.f;
    __syncthreads();

    for (int t = 0; t < T_LEN; ++t) {
      // ---- waits (wave 0, lane-parallel): own t-1 / below t / ring slot --
      if (tid < 64) {
        int* p = nullptr; int tgt = 0;
        if (tid == 0 && t > 0)     { p = &ready[l * T_LEN + t - 1];        tgt = WPL; }
        if (tid == 1 && l > 0)     { p = &ready[(l - 1) * T_LEN + t];      tgt = WPL; }
        if (tid == 2 && t >= RING) { p = &ready[(l + 1) * T_LEN + t - RING];
                                     tgt = (l == NL - 1) ? 1 : WPL; }
        bool done = (p == nullptr) || (s_dead != 0);
        int  it = 0;
        while (!__all(done)) {
          if (!done) {
            if (__hip_atomic_load(p, __ATOMIC_RELAXED, __HIP_MEMORY_SCOPE_AGENT) >= tgt)
              done = true;
            else if (++it >= SPIN_CAP) { s_dead = 1; done = true; }
            else __builtin_amdgcn_s_sleep(2);
          }
        }
        if (tid == 0) __builtin_amdgcn_fence(__ATOMIC_ACQUIRE, "agent");
      }
      __syncthreads();

      // ---- stage A-tile [32][512] bf16: thread (sm,sc) owns a 16-col h slab
      //      (TWO v8s per slab — R6's single-v8s holes were the NaN source)
      {
        const int sm = tid >> 4, sc = tid & 15;
        const v8s z = {0, 0, 0, 0, 0, 0, 0, 0};
        if (l == 0) {
          // x fp32 -> bf16, k [0,128)  (8 cols/thread: full coverage)
          const float* xs = x + ((size_t)t * B_SZ + sm) * IN_D + sc * 8;
          const float4 f0 = *(const float4*)xs, f1 = *(const float4*)(xs + 4);
          v8s p;
          p[0] = (short)f2bf(f0.x); p[1] = (short)f2bf(f0.y);
          p[2] = (short)f2bf(f0.z); p[3] = (short)f2bf(f0.w);
          p[4] = (short)f2bf(f1.x); p[5] = (short)f2bf(f1.y);
          p[6] = (short)f2bf(f1.z); p[7] = (short)f2bf(f1.w);
          *(v8s*)&Ash[sm][sc * 8] = p;
          // own h, k [128,384): 16 cols/thread -> two v8s
          if (t == 0) {
            *(v8s*)&Ash[sm][IN_D + sc * 16]     = z;
            *(v8s*)&Ash[sm][IN_D + sc * 16 + 8] = z;
          } else {
            const unsigned short* ho = hbuf
              + ((size_t)l * RING + (t - 1) % RING) * B_SZ * H_D + sm * H_D + sc * 16;
            *(v8s*)&Ash[sm][IN_D + sc * 16]     = *(const v8s*)ho;
            *(v8s*)&Ash[sm][IN_D + sc * 16 + 8] = *(const v8s*)(ho + 8);
          }
          // zero tail k [384,512)  (8 cols/thread: full coverage)
          *(v8s*)&Ash[sm][384 + sc * 8] = z;
        } else {
          // below h, k [0,256): two v8s
          const unsigned short* hb = hbuf
            + ((size_t)(l - 1) * RING + t % RING) * B_SZ * H_D + sm * H_D + sc * 16;
          *(v8s*)&Ash[sm][sc * 16]     = *(const v8s*)hb;
          *(v8s*)&Ash[sm][sc * 16 + 8] = *(const v8s*)(hb + 8);
          // own h, k [256,512): two v8s
          if (t == 0) {
            *(v8s*)&Ash[sm][H_D + sc * 16]     = z;
            *(v8s*)&Ash[sm][H_D + sc * 16 + 8] = z;
          } else {
            const unsigned short* ho = hbuf
              + ((size_t)l * RING + (t - 1) % RING) * B_SZ * H_D + sm * H_D + sc * 16;
            *(v8s*)&Ash[sm][H_D + sc * 16]     = *(const v8s*)ho;
            *(v8s*)&Ash[sm][H_D + sc * 16 + 8] = *(const v8s*)(ho + 8);
          }
        }
      }
      __syncthreads();

      // ---- MFMA: D[m][n] = A[m][k] * W^T[k][n], 2 M-tiles x 16 k-steps ----
      v4f acc0 = {0.f, 0.f, 0.f, 0.f}, acc1 = {0.f, 0.f, 0.f, 0.f};
#pragma unroll
      for (int ks = 0; ks < 16; ++ks) {
        const v8s a0 = *(const v8s*)&Ash[cc][ks * 32 + kq * 8];        // m 0..15
        const v8s a1 = *(const v8s*)&Ash[16 + cc][ks * 32 + kq * 8];   // m 16..31
        acc0 = __builtin_amdgcn_mfma_f32_16x16x32_bf16(a0, wfrag[ks], acc0, 0, 0, 0);
        acc1 = __builtin_amdgcn_mfma_f32_16x16x32_bf16(a1, wfrag[ks], acc1, 0, 0, 0);
      }
      // C/D layout: col = lane&15 (n), row = (lane>>4)*4 + q (m)
      {
        const int gate = w >> 1, ub = (w & 1) * 16;
#pragma unroll
        for (int q = 0; q < 4; ++q) {
          Gb[gate][kq * 4 + q][ub + cc]      = acc0[q];
          Gb[gate][16 + kq * 4 + q][ub + cc] = acc1[q];
        }
      }
      __syncthreads();

      // ---- gates (fp32): i,f,g,o; units 2*a2, 2*a2+1; batch mm ----
      {
        const float i0 = sigf (Gb[0][mm][2 * a2]     + bs[0][0]);
        const float i1 = sigf (Gb[0][mm][2 * a2 + 1] + bs[0][1]);
        const float f0 = sigf (Gb[1][mm][2 * a2]     + bs[1][0]);
        const float f1 = sigf (Gb[1][mm][2 * a2 + 1] + bs[1][1]);
        const float g0 = tanhf(Gb[2][mm][2 * a2]     + bs[2][0]);
        const float g1 = tanhf(Gb[2][mm][2 * a2 + 1] + bs[2][1]);
        const float o0 = sigf (Gb[3][mm][2 * a2]     + bs[3][0]);
        const float o1 = sigf (Gb[3][mm][2 * a2 + 1] + bs[3][1]);
        c0 = f0 * c0 + i0 * g0;
        c1 = f1 * c1 + i1 * g1;
        const float h0 = o0 * tanhf(c0);
        const float h1 = o1 * tanhf(c1);
        unsigned int hp = (unsigned int)f2bf(h0) | ((unsigned int)f2bf(h1) << 16);
        unsigned int* dst = (unsigned int*)(hbuf
          + ((size_t)l * RING + t % RING) * B_SZ * H_D + mm * H_D + g * UPW + 2 * a2);
        __hip_atomic_store(dst, hp, __ATOMIC_RELAXED, __HIP_MEMORY_SCOPE_AGENT);
      }
      asm volatile("s_waitcnt vmcnt(0)" ::: "memory");  // h performed at L3
      __syncthreads();
      if (tid == 0)
        __hip_atomic_fetch_add(&ready[l * T_LEN + t], 1,
                               __ATOMIC_RELAXED, __HIP_MEMORY_SCOPE_AGENT);
    }
  } else {
    // ------------------------- output-projection WG -----------------------
    float* h8  = (float*)&Ash[0][0];        // [32][260] fp32 (33280B <= Ash)
    float* WoL = (float*)&Gb[0][0][0];      // [2][256]
    for (int i = tid; i < OUT_D * H_D; i += NTHR) WoL[i] = Wo[i];
    const float bo0 = bo[0], bo1 = bo[1];
    __syncthreads();

    for (int t = 0; t < T_LEN; ++t) {
      if (tid < 64) {
        bool done = (tid != 0) || (s_dead != 0);
        int  it = 0;
        while (!__all(done)) {
          if (!done) {
            if (__hip_atomic_load(&ready[(NL - 1) * T_LEN + t],
                                  __ATOMIC_RELAXED, __HIP_MEMORY_SCOPE_AGENT) >= WPL)
              done = true;
            else if (++it >= SPIN_CAP) { s_dead = 1; done = true; }
            else __builtin_amdgcn_s_sleep(2);
          }
        }
        if (tid == 0) __builtin_amdgcn_fence(__ATOMIC_ACQUIRE, "agent");
      }
      __syncthreads();

      {
        const int sm = tid >> 4, sc = tid & 15;
        const unsigned short* hs = hbuf
          + ((size_t)(NL - 1) * RING + t % RING) * B_SZ * H_D + sm * H_D + sc * 16;
        const v8s v0 = *(const v8s*)hs, v1 = *(const v8s*)(hs + 8);
#pragma unroll
        for (int j = 0; j < 8; ++j) h8[sm * 260 + sc * 16 + j]     = bf2f((unsigned short)v0[j]);
#pragma unroll
        for (int j = 0; j < 8; ++j) h8[sm * 260 + sc * 16 + 8 + j] = bf2f((unsigned short)v1[j]);
      }
      __syncthreads();

      if (tid < B_SZ * OUT_D) {
        const int bb = tid >> 1, o = tid & 1;
        float s = 0.f;
#pragma unroll 8
        for (int k = 0; k < H_D; ++k) s += h8[bb * 260 + k] * WoL[o * H_D + k];
        s += (o ? bo1 : bo0);
        __hip_atomic_store(&out[(size_t)t * B_SZ * OUT_D + bb * OUT_D + o], sigf(s),
                           __ATOMIC_RELAXED, __HIP_MEMORY_SCOPE_AGENT);
      }
      asm volatile("s_waitcnt vmcnt(0)" ::: "memory");
      __syncthreads();
      if (tid == 0)
        __hip_atomic_fetch_add(&ready[NL * T_LEN + t], 1,
                               __ATOMIC_RELAXED, __HIP_MEMORY_SCOPE_AGENT);
    }
  }
}

extern "C" void kernel_launch(void* const* d_in, const int* in_sizes, int n_in,
                              void* d_out, int out_size, void* d_ws, size_t ws_size,
                              hipStream_t stream) {
  const float* x    = (const float*)d_in[0];
  const float* Wih0 = (const float*)d_in[1];
  const float* WihR = (const float*)d_in[2];
  const float* Whh  = (const float*)d_in[3];
  const float* bv   = (const float*)d_in[4];
  const float* Wo   = (const float*)d_in[5];
  const float* bo   = (const float*)d_in[6];
  float* out = (float*)d_out;

  int*            ready = (int*)d_ws;
  unsigned short* hbuf  = (unsigned short*)((char*)d_ws + (size_t)(NL + 1) * T_LEN * sizeof(int));

  // flags must start at 0 every call (ws is poisoned 0xAA before each launch)
  hipMemsetAsync(d_ws, 0, (size_t)(NL + 1) * T_LEN * sizeof(int), stream);

  hipLaunchKernelGGL(lstm_pipe, dim3(NPWG + 1), dim3(NTHR), 0, stream,
                     x, Wih0, WihR, Whh, bv, Wo, bo, out, ready, hbuf);
}